// Round 15
// baseline (242.071 us; speedup 1.0000x reference)
//
#include <hip/hip_runtime.h>
#include <hip/hip_bf16.h>
#include <cstddef>

#define BS 8
#define NQ 900
#define DM 256
#define LEN_V 13294

using bf16x8 = __attribute__((ext_vector_type(8))) __bf16;
using f32x4  = __attribute__((ext_vector_type(4))) float;

__device__ __forceinline__ unsigned short f2bf(float f) {
    union { float f; unsigned int u; } v; v.f = f;
    unsigned int r = v.u + 0x7FFFu + ((v.u >> 16) & 1u);
    return (unsigned short)(r >> 16);
}
__device__ __forceinline__ float bf2f(unsigned short u) {
    union { unsigned int u; float f; } v; v.u = ((unsigned int)u) << 16;
    return v.f;
}

#define SW(r) (((r) + ((r) >> 2)) & 3)

#define FLAG_RELU 1
#define FLAG_OBF  2
#define FLAG_SWAP 4
#define FLAG_QKV  8

#define AS1(p) ((const __attribute__((address_space(1))) void*)(p))
#define AS3(p) ((__attribute__((address_space(3))) void*)(p))

// Counted DMA waits (T4): 3 DMA ops per wave per STAGE -> vmcnt(3) means the
// previous buffer's loads landed while the new prefetch stays in flight.
#define VMW3() do {                                        \
    __builtin_amdgcn_sched_barrier(0);                     \
    asm volatile("s_waitcnt vmcnt(3)" ::: "memory");       \
    __builtin_amdgcn_sched_barrier(0);                     \
} while (0)
#define VMW0() do {                                        \
    __builtin_amdgcn_sched_barrier(0);                     \
    asm volatile("s_waitcnt vmcnt(0)" ::: "memory");       \
    __builtin_amdgcn_sched_barrier(0);                     \
} while (0)

// ---------------------------------------------------------------------------
// Batched weight prep: fp32 W[K][N] -> bf16 WT[N][K], optional scale
// ---------------------------------------------------------------------------
struct WDesc { const float* src; unsigned short* dst; int K; int N; float scale; };
struct WPrepArgs { WDesc w[10]; };

__global__ __launch_bounds__(256) void wprep_kernel(WPrepArgs args)
{
    WDesc d = args.w[blockIdx.z];
    int k0 = blockIdx.x * 32;
    int n0 = blockIdx.y * 32;
    if (k0 >= d.K || n0 >= d.N) return;
    __shared__ unsigned short t[32][33];
    int tx = threadIdx.x & 31, ty = threadIdx.x >> 5;
    #pragma unroll
    for (int i = 0; i < 4; ++i) {
        int kk = ty + i * 8;
        t[kk][tx] = f2bf(d.src[(size_t)(k0 + kk) * d.N + n0 + tx] * d.scale);
    }
    __syncthreads();
    #pragma unroll
    for (int i = 0; i < 4; ++i) {
        int nn = ty + i * 8;
        d.dst[(size_t)(n0 + nn) * d.K + k0 + tx] = t[tx][nn];
    }
}

// ---------------------------------------------------------------------------
// Bias concat: bqkv[768] = bq*sc|bk|bv ; boffaw[384] = boff|baw
// ---------------------------------------------------------------------------
__global__ __launch_bounds__(256) void bias_concat_kernel(
    const float* __restrict__ bq, const float* __restrict__ bk,
    const float* __restrict__ bv, const float* __restrict__ boff,
    const float* __restrict__ baw, float* __restrict__ bqkv,
    float* __restrict__ boffaw)
{
    const float sc = 0.17677669529663687f;
    int t = blockIdx.x * 256 + threadIdx.x;
    if (t < 256)       bqkv[t] = bq[t] * sc;
    else if (t < 512)  bqkv[t] = bk[t - 256];
    else if (t < 768)  bqkv[t] = bv[t - 512];
    if (t < 256)       boffaw[t] = boff[t];
    else if (t < 384)  boffaw[t] = baw[t - 256];
}

// ===========================================================================
// VALUE GEMM v3: occupancy-first 8-wave shape (r14) + global_load_lds
// double-buffered staging with counted vmcnt (r13's verified sync pattern).
// BM=128, BN=128, BK=32; 512 threads; wave tile 64x32 (acc[4][2]).
// LDS: 2 x (A fp32 16KB + B bf16 8KB) = 48KB -> 3 blocks/CU (24 waves, 75%).
// Per wave per STAGE: 2 A-DMA + 1 B-DMA -> vmcnt(3) keeps prefetch in flight.
// ===========================================================================
__global__ __launch_bounds__(512) void gemm_val3(
    const float* __restrict__ A, const unsigned short* __restrict__ BT,
    const float* __restrict__ bias, unsigned short* __restrict__ C,
    int M, int N, int K)
{
    __shared__ uint4 SMEM[3072];   // buf b at b*1536: A 1024 u4 (fp32) | B 512 u4 (bf16)

    const int tid = threadIdx.x;          // 0..511
    const int lane = tid & 63;
    const int wave = tid >> 6;            // 0..7
    const int wm = wave >> 2;             // 0..1 (row half)
    const int wn = wave & 3;              // 0..3 (col quadrant)
    const int row0 = blockIdx.y * 128;
    const int col0 = blockIdx.x * 128;

    f32x4 acc[4][2];
    #pragma unroll
    for (int i = 0; i < 4; ++i)
        #pragma unroll
        for (int j = 0; j < 2; ++j)
            acc[i][j] = {0.f, 0.f, 0.f, 0.f};

    const int lr = lane & 15;
    const int lc = lane >> 4;

    // pre-swizzled per-lane GLOBAL source chunks (inverse of read-side XOR)
    const int achunk = (lane & 7) ^ ((lane >> 3) & 7);   // A: 8 slots of 16B/row
    const int bchunk = (lane & 3) ^ ((lane >> 2) & 3);   // B: 4 slots of 16B/row

    auto STAGE = [&](int k0, int buf) {   // 3 DMA per wave
        uint4* Ab = SMEM + buf * 1536;
        uint4* Bb = Ab + 1024;
        #pragma unroll
        for (int c = 0; c < 2; ++c) {           // A: 2 calls/wave (16 total)
            int a = wave * 2 + c;               // call covers rows a*8..a*8+7
            int gr = row0 + a * 8 + (lane >> 3);
            if (gr >= M) gr = M - 1;
            const float* g = A + (size_t)gr * K + k0 + achunk * 4;
            __builtin_amdgcn_global_load_lds(AS1(g), AS3(Ab + a * 64), 16, 0, 0);
        }
        {                                        // B: 1 call/wave (8 total)
            int r = wave * 16 + (lane >> 2);     // rows wave*16..+15
            const unsigned short* g = BT + (size_t)(col0 + r) * K + k0 + bchunk * 8;
            __builtin_amdgcn_global_load_lds(AS1(g), AS3(Bb + wave * 64), 16, 0, 0);
        }
    };

    auto MSTEP = [&](int buf) {
        const float* Af = (const float*)(SMEM + buf * 1536);
        const bf16x8* Bb8 = (const bf16x8*)(SMEM + buf * 1536 + 1024);
        bf16x8 af[4], bfr[2];
        #pragma unroll
        for (int mi = 0; mi < 4; ++mi) {
            int R = wm * 64 + mi * 16 + lr;
            int s0 = (2 * lc) ^ (R & 7);
            int s1 = (2 * lc + 1) ^ (R & 7);
            f32x4 a0 = *(const f32x4*)(Af + R * 32 + s0 * 4);
            f32x4 a1 = *(const f32x4*)(Af + R * 32 + s1 * 4);
            union { unsigned short us[8]; bf16x8 v; } u;
            u.us[0] = f2bf(a0[0]); u.us[1] = f2bf(a0[1]);
            u.us[2] = f2bf(a0[2]); u.us[3] = f2bf(a0[3]);
            u.us[4] = f2bf(a1[0]); u.us[5] = f2bf(a1[1]);
            u.us[6] = f2bf(a1[2]); u.us[7] = f2bf(a1[3]);
            af[mi] = u.v;
        }
        #pragma unroll
        for (int ni = 0; ni < 2; ++ni) {
            int R = wn * 32 + ni * 16 + lr;
            bfr[ni] = Bb8[R * 4 + (lc ^ (R & 3))];
        }
        #pragma unroll
        for (int mi = 0; mi < 4; ++mi)
            #pragma unroll
            for (int ni = 0; ni < 2; ++ni)
                acc[mi][ni] = __builtin_amdgcn_mfma_f32_16x16x32_bf16(
                    af[mi], bfr[ni], acc[mi][ni], 0, 0, 0);
    };

    const int NS = K >> 5;   // 8 (even)
    STAGE(0, 0);
    for (int s = 0; s < NS; s += 2) {
        STAGE((s + 1) * 32, 1);      // prefetch buf1 -> 6 in flight
        VMW3();                      // buf0 landed; buf1 flying
        __syncthreads();
        MSTEP(0);
        __syncthreads();             // all waves done reading buf0
        if (s + 2 < NS) {
            STAGE((s + 2) * 32, 0);  // prefetch buf0 -> 6 in flight
            VMW3();                  // buf1 landed; buf0 flying
        } else {
            VMW0();                  // tail: drain buf1
        }
        __syncthreads();
        MSTEP(1);
        __syncthreads();
    }
    VMW0();

    // bf16 epilogue via LDS repack -> coalesced 16B stores
    {
        unsigned short* RP = (unsigned short*)SMEM;  // [64][136] shorts
        float bval[2];
        #pragma unroll
        for (int ni = 0; ni < 2; ++ni) {
            int col = col0 + wn * 32 + ni * 16 + lr;
            bval[ni] = (col < N) ? bias[col] : 0.f;
        }
        #pragma unroll
        for (int h2 = 0; h2 < 2; ++h2) {
            __syncthreads();
            if (wm == h2) {
                #pragma unroll
                for (int ni = 0; ni < 2; ++ni) {
                    int colL = wn * 32 + ni * 16 + lr;
                    #pragma unroll
                    for (int mi = 0; mi < 4; ++mi) {
                        #pragma unroll
                        for (int rg = 0; rg < 4; ++rg) {
                            int rowL = mi * 16 + lc * 4 + rg;
                            RP[rowL * 136 + colL] = f2bf(acc[mi][ni][rg] + bval[ni]);
                        }
                    }
                }
            }
            __syncthreads();
            {
                int r = tid >> 3;          // 0..63
                int c = tid & 7;           // 0..7
                int grow = row0 + h2 * 64 + r;
                if (grow < M) {
                    #pragma unroll
                    for (int j = 0; j < 2; ++j) {
                        int cc = c * 2 + j;
                        int gcol = col0 + cc * 8;
                        uint4 vq = *(const uint4*)&RP[r * 136 + cc * 8];
                        *(uint4*)(C + (size_t)grow * N + gcol) = vq;
                    }
                }
            }
        }
    }
}

// ===========================================================================
// SMALL GEMM: BM=64, BN=64, BK=32; 4 waves (2x2), wave 32x32 (2x2 frags).
// (unchanged — proven in round 10)
// ===========================================================================
#define SLOADA(B, k0) do {                                                    \
    if constexpr (ABF) {                                                      \
        const unsigned short* ap_ = Abf + (size_t)agr * K + (k0) + ah;        \
        qa##B = aok ? *(const uint4*)ap_ : z4;                                \
    } else {                                                                  \
        if (aok) {                                                            \
            const float* ap_ = Afp + (size_t)agr * K + (k0) + ah;             \
            pa##B##0 = *(const f32x4*)(ap_);                                  \
            pa##B##1 = *(const f32x4*)(ap_ + 4);                              \
            if (A2) {                                                         \
                const float* a2_ = A2 + (size_t)agr * K + (k0) + ah;          \
                pa##B##0 += *(const f32x4*)(a2_);                             \
                pa##B##1 += *(const f32x4*)(a2_ + 4);                         \
            }                                                                 \
        } else { pa##B##0 = zf4; pa##B##1 = zf4; }                            \
    }                                                                         \
    { const unsigned short* bp_ = BT + (size_t)bgr * K + (k0) + ah;           \
      pb##B = *(const uint4*)bp_; }                                           \
} while (0)

#define SSTAGE(B) do {                                                        \
    if constexpr (ABF) {                                                      \
        As4[ar * 4 + (ac ^ SW(ar))] = qa##B;                                  \
    } else {                                                                  \
        union { unsigned short us_[8]; uint4 q_; } u_;                        \
        u_.us_[0] = f2bf(pa##B##0[0]); u_.us_[1] = f2bf(pa##B##0[1]);         \
        u_.us_[2] = f2bf(pa##B##0[2]); u_.us_[3] = f2bf(pa##B##0[3]);         \
        u_.us_[4] = f2bf(pa##B##1[0]); u_.us_[5] = f2bf(pa##B##1[1]);         \
        u_.us_[6] = f2bf(pa##B##1[2]); u_.us_[7] = f2bf(pa##B##1[3]);         \
        As4[ar * 4 + (ac ^ SW(ar))] = u_.q_;                                  \
    }                                                                         \
    Bs4[ar * 4 + (ac ^ SW(ar))] = pb##B;                                      \
} while (0)

#define SMFMA() do {                                                          \
    bf16x8 af[2], bfr[2];                                                     \
    _Pragma("unroll")                                                         \
    for (int mi = 0; mi < 2; ++mi) {                                          \
        int r = wm * 32 + mi * 16 + lr;                                       \
        af[mi] = Asb[r * 4 + (lc ^ SW(r))];                                   \
    }                                                                         \
    _Pragma("unroll")                                                         \
    for (int ni = 0; ni < 2; ++ni) {                                          \
        int r = wn * 32 + ni * 16 + lr;                                       \
        bfr[ni] = Bsb[r * 4 + (lc ^ SW(r))];                                  \
    }                                                                         \
    _Pragma("unroll")                                                         \
    for (int mi = 0; mi < 2; ++mi)                                            \
        _Pragma("unroll")                                                     \
        for (int ni = 0; ni < 2; ++ni)                                        \
            acc[mi][ni] = __builtin_amdgcn_mfma_f32_16x16x32_bf16(            \
                af[mi], bfr[ni], acc[mi][ni], 0, 0, 0);                       \
} while (0)

template<int ABF>
__global__ __launch_bounds__(256) void gemm_small(
    const void* __restrict__ Ain, const float* __restrict__ A2,
    const unsigned short* __restrict__ BT, const float* __restrict__ bias,
    void* __restrict__ Cout, int M, int N, int K, int flags)
{
    __shared__ uint4 SMEM[512];
    uint4* As4 = SMEM;
    uint4* Bs4 = SMEM + 256;

    const int tid = threadIdx.x;
    const int lane = tid & 63;
    const int wave = tid >> 6;
    const int wm = wave >> 1;
    const int wn = wave & 1;
    const int row0 = (flags & FLAG_SWAP ? blockIdx.y : blockIdx.x) * 64;
    const int col0 = (flags & FLAG_SWAP ? blockIdx.x : blockIdx.y) * 64;
    if ((flags & FLAG_QKV) && col0 >= 512) A2 = nullptr;

    const float* Afp = (const float*)Ain;
    const unsigned short* Abf = (const unsigned short*)Ain;

    f32x4 acc[2][2];
    #pragma unroll
    for (int i = 0; i < 2; ++i)
        #pragma unroll
        for (int j = 0; j < 2; ++j)
            acc[i][j] = {0.f, 0.f, 0.f, 0.f};

    const int ar = tid >> 2;
    const int ac = tid & 3;
    const int ah = ac * 8;
    const int agr = row0 + ar;
    const bool aok = agr < M;
    const int bgr = col0 + ar;
    const int lr = lane & 15;
    const int lc = lane >> 4;

    const bf16x8* Asb = (const bf16x8*)As4;
    const bf16x8* Bsb = (const bf16x8*)Bs4;
    const uint4 z4 = {0u, 0u, 0u, 0u};
    const f32x4 zf4 = {0.f, 0.f, 0.f, 0.f};

    f32x4 pa00, pa01, pa10, pa11;
    uint4 qa0, qa1;
    uint4 pb0, pb1;

    const int nsteps = K >> 5;
    SLOADA(0, 0);
    for (int s = 0; s < nsteps; s += 2) {
        __syncthreads();
        SSTAGE(0);
        SLOADA(1, (s + 1 < nsteps ? (s + 1) * 32 : 0));
        __syncthreads();
        SMFMA();
        __syncthreads();
        SSTAGE(1);
        SLOADA(0, (s + 2 < nsteps ? (s + 2) * 32 : 0));
        __syncthreads();
        SMFMA();
    }

    const int relu = flags & FLAG_RELU;
    if (!(flags & FLAG_OBF)) {
        float* C = (float*)Cout;
        #pragma unroll
        for (int ni = 0; ni < 2; ++ni) {
            int col = col0 + wn * 32 + ni * 16 + lr;
            if (col >= N) continue;
            float bval = bias[col];
            #pragma unroll
            for (int mi = 0; mi < 2; ++mi) {
                #pragma unroll
                for (int rg = 0; rg < 4; ++rg) {
                    int row = row0 + wm * 32 + mi * 16 + lc * 4 + rg;
                    if (row < M) {
                        float o = acc[mi][ni][rg] + bval;
                        if (relu) o = fmaxf(o, 0.f);
                        C[(size_t)row * N + col] = o;
                    }
                }
            }
        }
    } else {
        unsigned short* RP = (unsigned short*)SMEM;
        unsigned short* C = (unsigned short*)Cout;
        float bval[2];
        #pragma unroll
        for (int ni = 0; ni < 2; ++ni) {
            int col = col0 + wn * 32 + ni * 16 + lr;
            bval[ni] = (col < N) ? bias[col] : 0.f;
        }
        #pragma unroll
        for (int h2 = 0; h2 < 2; ++h2) {
            __syncthreads();
            if (wm == h2) {
                #pragma unroll
                for (int ni = 0; ni < 2; ++ni) {
                    int colL = wn * 32 + ni * 16 + lr;
                    #pragma unroll
                    for (int mi = 0; mi < 2; ++mi) {
                        #pragma unroll
                        for (int rg = 0; rg < 4; ++rg) {
                            int rowL = mi * 16 + lc * 4 + rg;
                            float o = acc[mi][ni][rg] + bval[ni];
                            if (relu) o = fmaxf(o, 0.f);
                            RP[rowL * 72 + colL] = f2bf(o);
                        }
                    }
                }
            }
            __syncthreads();
            {
                int r = tid >> 3;
                int c = tid & 7;
                int grow = row0 + h2 * 32 + r;
                int gcol = col0 + c * 8;
                if (grow < M && gcol < N) {
                    uint4 vq = *(const uint4*)&RP[r * 72 + c * 8];
                    *(uint4*)(C + (size_t)grow * N + gcol) = vq;
                }
            }
        }
    }
}

// ---------------------------------------------------------------------------
// MFMA flash self-attention over fused bf16 QKV [M][768]
// ---------------------------------------------------------------------------
#define QKVS 768
__global__ __launch_bounds__(256) void attn_mfma_kernel(
    const unsigned short* __restrict__ qkv, float* __restrict__ out)
{
    __shared__ uint4 Kls[64 * 4];
    __shared__ uint4 Vtls[32 * 8];

    const int tid = threadIdx.x;
    const int lane = tid & 63;
    const int wave = tid >> 6;
    const int qcol = lane & 15;
    const int g = lane >> 4;
    const int bh = blockIdx.x;
    const int h = bh & 7, b = bh >> 3;
    const int qg = blockIdx.y * 64 + wave * 16 + qcol;
    const int qc = qg < NQ ? qg : NQ - 1;

    bf16x8 qf = *(const bf16x8*)(qkv + ((size_t)(b * NQ + qc)) * QKVS + h * 32 + g * 8);

    float mrun = -3.0e38f, lrun = 0.f;
    f32x4 oacc[2];
    oacc[0] = {0.f, 0.f, 0.f, 0.f};
    oacc[1] = {0.f, 0.f, 0.f, 0.f};
    const f32x4 zacc = {0.f, 0.f, 0.f, 0.f};

    const int kidx = tid >> 2, kdc = tid & 3;
    const int vkp = tid >> 3, vdc = tid & 7;
    const bf16x8* Kb = (const bf16x8*)Kls;
    const bf16x8* Vb = (const bf16x8*)Vtls;
    unsigned int* V32 = (unsigned int*)Vtls;

    for (int jb = 0; jb < NQ; jb += 64) {
        __syncthreads();
        {
            int gk = jb + kidx;
            const uint4 z = {0u, 0u, 0u, 0u};
            uint4 kv = (gk < NQ)
                ? *(const uint4*)(qkv + ((size_t)(b * NQ + gk)) * QKVS + 256 + h * 32 + kdc * 8)
                : z;
            Kls[kidx * 4 + (kdc ^ ((kidx >> 1) & 3))] = kv;
        }
        {
            int k0g = jb + 2 * vkp;
            ushort4 a = {0, 0, 0, 0}, c = {0, 0, 0, 0};
            if (k0g < NQ)
                a = *(const ushort4*)(qkv + ((size_t)(b * NQ + k0g)) * QKVS + 512 + h * 32 + vdc * 4);
            if (k0g + 1 < NQ)
                c = *(const ushort4*)(qkv + ((size_t)(b * NQ + k0g + 1)) * QKVS + 512 + h * 32 + vdc * 4);
            unsigned int p0 = (unsigned int)a.x | ((unsigned int)c.x << 16);
            unsigned int p1 = (unsigned int)a.y | ((unsigned int)c.y << 16);
            unsigned int p2 = (unsigned int)a.z | ((unsigned int)c.z << 16);
            unsigned int p3 = (unsigned int)a.w | ((unsigned int)c.w << 16);
            int d0 = vdc * 4;
            V32[(d0+0) * 32 + ((vkp >> 2) ^ ((d0+0) & 7)) * 4 + (vkp & 3)] = p0;
            V32[(d0+1) * 32 + ((vkp >> 2) ^ ((d0+1) & 7)) * 4 + (vkp & 3)] = p1;
            V32[(d0+2) * 32 + ((vkp >> 2) ^ ((d0+2) & 7)) * 4 + (vkp & 3)] = p2;
            V32[(d0+3) * 32 + ((vkp >> 2) ^ ((d0+3) & 7)) * 4 + (vkp & 3)] = p3;
        }
        __syncthreads();

        f32x4 sacc[4];
        #pragma unroll
        for (int kt = 0; kt < 4; ++kt) {
            int key = kt * 16 + qcol;
            bf16x8 kf = Kb[key * 4 + (g ^ ((key >> 1) & 3))];
            sacc[kt] = __builtin_amdgcn_mfma_f32_16x16x32_bf16(kf, qf, zacc, 0, 0, 0);
        }
        if (jb + 64 > NQ) {
            #pragma unroll
            for (int kt = 0; kt < 4; ++kt)
                #pragma unroll
                for (int r = 0; r < 4; ++r)
                    if (jb + kt * 16 + 4 * g + r >= NQ) sacc[kt][r] = -3.0e38f;
        }

        float mloc = -3.0e38f;
        #pragma unroll
        for (int kt = 0; kt < 4; ++kt)
            #pragma unroll
            for (int r = 0; r < 4; ++r)
                mloc = fmaxf(mloc, sacc[kt][r]);
        mloc = fmaxf(mloc, __shfl_xor(mloc, 16));
        mloc = fmaxf(mloc, __shfl_xor(mloc, 32));
        float mnew = fmaxf(mrun, mloc);
        float corr = __expf(mrun - mnew);
        mrun = mnew;

        float lloc = 0.f;
        unsigned int pk2[4][2];
        #pragma unroll
        for (int kt = 0; kt < 4; ++kt) {
            float p0 = __expf(sacc[kt][0] - mnew);
            float p1 = __expf(sacc[kt][1] - mnew);
            float p2 = __expf(sacc[kt][2] - mnew);
            float p3 = __expf(sacc[kt][3] - mnew);
            lloc += p0 + p1 + p2 + p3;
            pk2[kt][0] = (unsigned int)f2bf(p0) | ((unsigned int)f2bf(p1) << 16);
            pk2[kt][1] = (unsigned int)f2bf(p2) | ((unsigned int)f2bf(p3) << 16);
        }
        lloc += __shfl_xor(lloc, 16);
        lloc += __shfl_xor(lloc, 32);
        lrun = lrun * corr + lloc;
        #pragma unroll
        for (int ni = 0; ni < 2; ++ni)
            #pragma unroll
            for (int r = 0; r < 4; ++r)
                oacc[ni][r] *= corr;

        const int s0 = qcol + 32 * (g & 1);
        const bool hi = (g >> 1) != 0;
        #pragma unroll
        for (int tp = 0; tp < 2; ++tp) {
            int A0 = (int)pk2[2 * tp][0], A1 = (int)pk2[2 * tp][1];
            int B0 = (int)pk2[2 * tp + 1][0], B1 = (int)pk2[2 * tp + 1][1];
            int a0 = __shfl(A0, s0),      a1 = __shfl(A1, s0);
            int b0 = __shfl(B0, s0),      b1 = __shfl(B1, s0);
            int a2 = __shfl(A0, s0 + 16), a3 = __shfl(A1, s0 + 16);
            int b2 = __shfl(B0, s0 + 16), b3 = __shfl(B1, s0 + 16);
            union { unsigned int u[4]; bf16x8 v8; } pf;
            pf.u[0] = hi ? (unsigned int)b0 : (unsigned int)a0;
            pf.u[1] = hi ? (unsigned int)b1 : (unsigned int)a1;
            pf.u[2] = hi ? (unsigned int)b2 : (unsigned int)a2;
            pf.u[3] = hi ? (unsigned int)b3 : (unsigned int)a3;
            #pragma unroll
            for (int ni = 0; ni < 2; ++ni) {
                int d = ni * 16 + qcol;
                bf16x8 vf = Vb[d * 8 + ((4 * tp + g) ^ (d & 7))];
                oacc[ni] = __builtin_amdgcn_mfma_f32_16x16x32_bf16(vf, pf.v8, oacc[ni], 0, 0, 0);
            }
        }
    }

    if (qg < NQ) {
        float inv = 1.f / lrun;
        float* op = out + ((size_t)(b * NQ + qg)) * DM + h * 32;
        float4 o0, o1;
        o0.x = oacc[0][0] * inv; o0.y = oacc[0][1] * inv;
        o0.z = oacc[0][2] * inv; o0.w = oacc[0][3] * inv;
        o1.x = oacc[1][0] * inv; o1.y = oacc[1][1] * inv;
        o1.z = oacc[1][2] * inv; o1.w = oacc[1][3] * inv;
        *(float4*)(op + 4 * g) = o0;
        *(float4*)(op + 16 + 4 * g) = o1;
    }
}

// ---------------------------------------------------------------------------
// Deformable sampling over bf16 value table; offaw [M][384] holds RAW aw
// logits at +256 — softmax over 16 computed inline.
// ---------------------------------------------------------------------------
__global__ __launch_bounds__(256) void deform_kernel(
    const unsigned short* __restrict__ value, const float* __restrict__ offaw,
    const float* __restrict__ rbbox, float* __restrict__ dout)
{
    int t = blockIdx.x * 256 + threadIdx.x;
    if (t >= BS * NQ * 64) return;
    int c = t & 7;
    int h = (t >> 3) & 7;
    int bq = t >> 6;
    int b = bq / NQ;

    const int Hs[4]     = {100, 50, 25, 13};
    const int Wsz[4]    = {100, 50, 25, 13};
    const int Starts[4] = {0, 10000, 12500, 13125};

    float4 rb = *(const float4*)(rbbox + (size_t)bq * 4);
    const float* offp = offaw + (size_t)bq * 384 + h * 32;
    const float* awp  = offaw + (size_t)bq * 384 + 256 + h * 16;
    const unsigned short* vb = value + ((size_t)b * LEN_V) * 256 + h * 32 + c * 4;

    float awv[16];
    #pragma unroll
    for (int i = 0; i < 4; ++i) {
        float4 f = *(const float4*)(awp + i * 4);
        awv[4*i+0] = f.x; awv[4*i+1] = f.y; awv[4*i+2] = f.z; awv[4*i+3] = f.w;
    }
    float mx = awv[0];
    #pragma unroll
    for (int i = 1; i < 16; ++i) mx = fmaxf(mx, awv[i]);
    float ssum = 0.f;
    #pragma unroll
    for (int i = 0; i < 16; ++i) { awv[i] = __expf(awv[i] - mx); ssum += awv[i]; }
    float sinv = 1.f / ssum;

    float4 acc = make_float4(0.f, 0.f, 0.f, 0.f);
    #pragma unroll
    for (int l = 0; l < 4; ++l) {
        const int H = Hs[l], W = Wsz[l], st = Starts[l];
        #pragma unroll
        for (int p = 0; p < 4; ++p) {
            float ox = offp[l * 8 + p * 2 + 0];
            float oy = offp[l * 8 + p * 2 + 1];
            float a_w = awv[l * 4 + p] * sinv;
            float xx = (rb.x + ox * 0.125f * rb.z) * W - 0.5f;
            float yy = (rb.y + oy * 0.125f * rb.w) * H - 0.5f;
            float x0f = floorf(xx), y0f = floorf(yy);
            float fx = xx - x0f, fy = yy - y0f;
            int x0 = (int)x0f, y0 = (int)y0f;
            #pragma unroll
            for (int dy = 0; dy < 2; ++dy) {
                int yi = y0 + dy;
                float wy = dy ? fy : (1.f - fy);
                bool vy = (yi >= 0) && (yi < H);
                int yc = min(max(yi, 0), H - 1);
                #pragma unroll
                for (int dx = 0; dx < 2; ++dx) {
                    int xi = x0 + dx;
                    float wx = dx ? fx : (1.f - fx);
                    bool vx = (xi >= 0) && (xi < W);
                    int xc = min(max(xi, 0), W - 1);
                    float wgt = a_w * wy * wx * ((vx && vy) ? 1.f : 0.f);
                    ushort4 gv = *(const ushort4*)(vb + (size_t)(st + yc * W + xc) * 256);
                    acc.x += wgt * bf2f(gv.x); acc.y += wgt * bf2f(gv.y);
                    acc.z += wgt * bf2f(gv.z); acc.w += wgt * bf2f(gv.w);
                }
            }
        }
    }
    *(float4*)(dout + (size_t)bq * 256 + h * 32 + c * 4) = acc;
}

// ---------------------------------------------------------------------------
__global__ __launch_bounds__(256) void ln_kernel(
    const float* __restrict__ x, const float* __restrict__ dx,
    const float* __restrict__ g, const float* __restrict__ bt,
    float* __restrict__ out, int rows)
{
    int row = blockIdx.x * 4 + (threadIdx.x >> 6);
    if (row >= rows) return;
    int lane = threadIdx.x & 63;
    size_t base = (size_t)row * 256 + lane * 4;
    float4 xv = *(const float4*)(x + base);
    float4 dv = *(const float4*)(dx + base);
    float a0 = xv.x + dv.x, a1 = xv.y + dv.y, a2 = xv.z + dv.z, a3 = xv.w + dv.w;
    float s = a0 + a1 + a2 + a3;
    float s2 = a0 * a0 + a1 * a1 + a2 * a2 + a3 * a3;
    #pragma unroll
    for (int o = 32; o; o >>= 1) {
        s += __shfl_xor(s, o);
        s2 += __shfl_xor(s2, o);
    }
    float mean = s * (1.f / 256.f);
    float var = s2 * (1.f / 256.f) - mean * mean;
    float inv = rsqrtf(var + 1e-5f);
    float4 gv = *(const float4*)(g + lane * 4);
    float4 bv = *(const float4*)(bt + lane * 4);
    float4 r;
    r.x = (a0 - mean) * inv * gv.x + bv.x;
    r.y = (a1 - mean) * inv * gv.y + bv.y;
    r.z = (a2 - mean) * inv * gv.z + bv.z;
    r.w = (a3 - mean) * inv * gv.w + bv.w;
    *(float4*)(out + base) = r;
}

// ---------------------------------------------------------------------------
extern "C" void kernel_launch(void* const* d_in, const int* in_sizes, int n_in,
                              void* d_out, int out_size, void* d_ws, size_t ws_size,
                              hipStream_t stream)
{
    const float* embed = (const float*)d_in[0];
    const float* rbbox = (const float*)d_in[1];
    const float* feats = (const float*)d_in[2];
    const float* qpos  = (const float*)d_in[3];
    const float* Wq = (const float*)d_in[4];  const float* bq = (const float*)d_in[5];
    const float* Wk = (const float*)d_in[6];  const float* bk = (const float*)d_in[7];
    const float* Wv = (const float*)d_in[8];  const float* bv = (const float*)d_in[9];
    const float* Wo = (const float*)d_in[10]; const float* bo = (const float*)d_in[11];
    const float* g1 = (const float*)d_in[12]; const float* b1 = (const float*)d_in[13];
    const float* Wval = (const float*)d_in[14]; const float* bval = (const float*)d_in[15];
    const float* Woff = (const float*)d_in[16]; const float* boff = (const float*)d_in[17];
    const float* Waw  = (const float*)d_in[18]; const float* baw  = (const float*)d_in[19];
    const float* Wop  = (const float*)d_in[20]; const float* bop  = (const float*)d_in[21];
    const float* g2 = (const float*)d_in[22]; const float* b2 = (const float*)d_in[23];
    const float* W1 = (const float*)d_in[24]; const float* bf1 = (const float*)d_in[25];
    const float* W2 = (const float*)d_in[26]; const float* bf2 = (const float*)d_in[27];
    const float* g3 = (const float*)d_in[28]; const float* b3 = (const float*)d_in[29];

    const int M = BS * NQ;                 // 7200
    const int MV = BS * LEN_V;             // 106352
    const size_t E = (size_t)M * DM;       // 1,843,200 floats
    const size_t VAL = (size_t)MV * DM;    // value region (floats)

    float* ws = (float*)d_ws;
    float* valueb = ws;
    float* qkvreg = ws + VAL;
    float* attb   = qkvreg + 3 * E;
    float* e1b    = attb + E;
    unsigned short* wbase = (unsigned short*)(e1b + E);
    unsigned short* wqkv_t   = wbase;                     // 768*256
    unsigned short* wo_t     = wbase + 196608;
    unsigned short* wval_t   = wbase + 262144;
    unsigned short* woffaw_t = wbase + 327680;
    unsigned short* wop_t    = wbase + 425984;
    unsigned short* w1_t     = wbase + 491520;
    unsigned short* w2_t     = wbase + 753664;
    float* bqkv   = (float*)(wbase + 1015808);
    float* boffaw = bqkv + 768;

    unsigned short* valuebf = (unsigned short*)valueb;
    unsigned short* qkvbf   = (unsigned short*)qkvreg;
    float* sab    = qkvreg;
    float* offawb = qkvreg + E;
    float* doutb  = attb;
    float* cab    = qkvreg;
    float* e2b    = qkvreg + 2 * E;
    unsigned short* ffhb = (unsigned short*)valueb;
    float* ffb    = attb;

    dim3 blk(256);
    auto gsS = [](int m, int n) { return dim3((n + 63) / 64, (m + 63) / 64); };

    // 0: weight + bias prep (Wq pre-scaled by 1/sqrt(HEAD_DIM))
    {
        const float sc = 0.17677669529663687f;
        WPrepArgs a;
        a.w[0] = {Wq,   wqkv_t,                 256, 256,  sc};
        a.w[1] = {Wk,   wqkv_t + 256 * 256,     256, 256,  1.f};
        a.w[2] = {Wv,   wqkv_t + 512 * 256,     256, 256,  1.f};
        a.w[3] = {Wo,   wo_t,                   256, 256,  1.f};
        a.w[4] = {Wval, wval_t,                 256, 256,  1.f};
        a.w[5] = {Woff, woffaw_t,               256, 256,  1.f};
        a.w[6] = {Waw,  woffaw_t + 256 * 256,   256, 128,  1.f};
        a.w[7] = {Wop,  wop_t,                  256, 256,  1.f};
        a.w[8] = {W1,   w1_t,                   256, 1024, 1.f};
        a.w[9] = {W2,   w2_t,                   1024, 256, 1.f};
        wprep_kernel<<<dim3(32, 32, 10), blk, 0, stream>>>(a);
        bias_concat_kernel<<<dim3(3), blk, 0, stream>>>(bq, bk, bv, boff, baw, bqkv, boffaw);
    }

    // 1: fused QKV projection -> bf16 [M][768]
    gemm_small<0><<<gsS(M, 768), blk, 0, stream>>>(embed, qpos, wqkv_t, bqkv, qkvbf, M, 768, 256, FLAG_SWAP | FLAG_QKV | FLAG_OBF);
    // 2: self-attention (MFMA flash, bf16 inputs)
    attn_mfma_kernel<<<dim3(BS * 8, (NQ + 63) / 64), blk, 0, stream>>>(qkvbf, attb);
    // 3: output projection
    gemm_small<0><<<gsS(M, 256), blk, 0, stream>>>(attb, nullptr, wo_t, bo, sab, M, 256, 256, FLAG_SWAP);
    // 4: LN1
    ln_kernel<<<dim3((M + 3) / 4), blk, 0, stream>>>(embed, sab, g1, b1, e1b, M);
    // 5: value projection: 8-wave + DMA double-buffer + counted vmcnt -> bf16
    gemm_val3<<<dim3(2, (MV + 127) / 128), dim3(512), 0, stream>>>(feats, wval_t, bval, valuebf, MV, 256, 256);
    // 6: fused offsets + aw logits (query = e1 + qpos); softmax fused into deform
    gemm_small<0><<<gsS(M, 384), blk, 0, stream>>>(e1b, qpos, woffaw_t, boffaw, offawb, M, 384, 256, FLAG_SWAP);
    // 7: deformable sampling (bf16 gathers, inline aw softmax)
    deform_kernel<<<dim3((BS * NQ * 64 + 255) / 256), blk, 0, stream>>>(valuebf, offawb, rbbox, doutb);
    // 8: output projection of deformable attention
    gemm_small<0><<<gsS(M, 256), blk, 0, stream>>>(doutb, nullptr, wop_t, bop, cab, M, 256, 256, FLAG_SWAP);
    // 9: LN2
    ln_kernel<<<dim3((M + 3) / 4), blk, 0, stream>>>(e1b, cab, g2, b2, e2b, M);
    // 10: FFN1 (relu) -> bf16 hidden
    gemm_small<0><<<gsS(M, 1024), blk, 0, stream>>>(e2b, nullptr, w1_t, bf1, ffhb, M, 1024, 256, FLAG_SWAP | FLAG_RELU | FLAG_OBF);
    // 11: FFN2 (bf16 A, K=1024)
    gemm_small<1><<<gsS(M, 256), blk, 0, stream>>>(ffhb, nullptr, w2_t, bf2, ffb, M, 256, 1024, FLAG_SWAP);
    // 12: LN3 -> out
    ln_kernel<<<dim3((M + 3) / 4), blk, 0, stream>>>(e2b, ffb, g3, b3, (float*)d_out, M);
}

// Round 16
// 233.878 us; speedup vs baseline: 1.0350x; 1.0350x over previous
//
#include <hip/hip_runtime.h>
#include <hip/hip_bf16.h>
#include <cstddef>

#define BS 8
#define NQ 900
#define DM 256
#define LEN_V 13294

using bf16x8 = __attribute__((ext_vector_type(8))) __bf16;
using f32x4  = __attribute__((ext_vector_type(4))) float;

__device__ __forceinline__ unsigned short f2bf(float f) {
    union { float f; unsigned int u; } v; v.f = f;
    unsigned int r = v.u + 0x7FFFu + ((v.u >> 16) & 1u);
    return (unsigned short)(r >> 16);
}
__device__ __forceinline__ float bf2f(unsigned short u) {
    union { unsigned int u; float f; } v; v.u = ((unsigned int)u) << 16;
    return v.f;
}

#define SW(r) (((r) + ((r) >> 2)) & 3)

#define FLAG_RELU 1
#define FLAG_OBF  2
#define FLAG_SWAP 4
#define FLAG_QKV  8

// ---------------------------------------------------------------------------
// Batched weight prep: fp32 W[K][N] -> bf16 WT[N][K], optional scale
// ---------------------------------------------------------------------------
struct WDesc { const float* src; unsigned short* dst; int K; int N; float scale; };
struct WPrepArgs { WDesc w[10]; };

__global__ __launch_bounds__(256) void wprep_kernel(WPrepArgs args)
{
    WDesc d = args.w[blockIdx.z];
    int k0 = blockIdx.x * 32;
    int n0 = blockIdx.y * 32;
    if (k0 >= d.K || n0 >= d.N) return;
    __shared__ unsigned short t[32][33];
    int tx = threadIdx.x & 31, ty = threadIdx.x >> 5;
    #pragma unroll
    for (int i = 0; i < 4; ++i) {
        int kk = ty + i * 8;
        t[kk][tx] = f2bf(d.src[(size_t)(k0 + kk) * d.N + n0 + tx] * d.scale);
    }
    __syncthreads();
    #pragma unroll
    for (int i = 0; i < 4; ++i) {
        int nn = ty + i * 8;
        d.dst[(size_t)(n0 + nn) * d.K + k0 + tx] = t[tx][nn];
    }
}

// ---------------------------------------------------------------------------
// Bias concat: bqkv[768] = bq*sc|bk|bv ; boffaw[384] = boff|baw
// ---------------------------------------------------------------------------
__global__ __launch_bounds__(256) void bias_concat_kernel(
    const float* __restrict__ bq, const float* __restrict__ bk,
    const float* __restrict__ bv, const float* __restrict__ boff,
    const float* __restrict__ baw, float* __restrict__ bqkv,
    float* __restrict__ boffaw)
{
    const float sc = 0.17677669529663687f;
    int t = blockIdx.x * 256 + threadIdx.x;
    if (t < 256)       bqkv[t] = bq[t] * sc;
    else if (t < 512)  bqkv[t] = bk[t - 256];
    else if (t < 768)  bqkv[t] = bv[t - 512];
    if (t < 256)       boffaw[t] = boff[t];
    else if (t < 384)  boffaw[t] = baw[t - 256];
}

// ===========================================================================
// VALUE GEMM v2 (round-14 proven, 63us @ 2.6TB/s, 65% occ): occupancy-first
// 8-wave / 512-thread shape, BM=128 x BN=128, single-buffered 16KB LDS,
// plain reg-staged loads, 2 barriers per K-step. TLP-bound: max waves wins
// (r13 counted-vmcnt null, r15 DMA+dbuf regressed via occupancy loss).
// ===========================================================================
__global__ __launch_bounds__(512) void gemm_val2(
    const float* __restrict__ A, const unsigned short* __restrict__ BT,
    const float* __restrict__ bias, unsigned short* __restrict__ C,
    int M, int N, int K)
{
    __shared__ uint4 SMEM[1088];   // staging: A 8KB + B 8KB; repack 17408B

    uint4* As4 = SMEM;             // [128 rows][4 chunks]
    uint4* Bs4 = SMEM + 512;       // [128 rows][4 chunks]

    const int tid = threadIdx.x;          // 0..511
    const int lane = tid & 63;
    const int wave = tid >> 6;            // 0..7
    const int wm = wave >> 2;             // 0..1  (row half)
    const int wn = wave & 3;              // 0..3  (col quadrant of 32)
    const int row0 = blockIdx.y * 128;
    const int col0 = blockIdx.x * 128;

    f32x4 acc[4][2];
    #pragma unroll
    for (int i = 0; i < 4; ++i)
        #pragma unroll
        for (int j = 0; j < 2; ++j)
            acc[i][j] = {0.f, 0.f, 0.f, 0.f};

    const int sr = tid >> 2;              // staging row 0..127
    const int sc = tid & 3;               // chunk 0..3 (8 elems)
    const int agr0 = row0 + sr;
    const int agr = agr0 < M ? agr0 : M - 1;   // clamp (outputs guarded)
    const int bgr = col0 + sr;                 // < 256 always
    const int lr = lane & 15;
    const int lc = lane >> 4;

    const bf16x8* Asb = (const bf16x8*)As4;
    const bf16x8* Bsb = (const bf16x8*)Bs4;

    for (int k0 = 0; k0 < K; k0 += 32) {
        const float* ap = A + (size_t)agr * K + k0 + sc * 8;
        f32x4 a0 = *(const f32x4*)ap;
        f32x4 a1 = *(const f32x4*)(ap + 4);
        uint4 bq = *(const uint4*)(BT + (size_t)bgr * K + k0 + sc * 8);

        __syncthreads();
        {
            union { unsigned short us[8]; uint4 q; } u;
            u.us[0] = f2bf(a0[0]); u.us[1] = f2bf(a0[1]);
            u.us[2] = f2bf(a0[2]); u.us[3] = f2bf(a0[3]);
            u.us[4] = f2bf(a1[0]); u.us[5] = f2bf(a1[1]);
            u.us[6] = f2bf(a1[2]); u.us[7] = f2bf(a1[3]);
            As4[sr * 4 + (sc ^ SW(sr))] = u.q;
        }
        Bs4[sr * 4 + (sc ^ SW(sr))] = bq;
        __syncthreads();

        bf16x8 af[4], bfr[2];
        #pragma unroll
        for (int mi = 0; mi < 4; ++mi) {
            int r = wm * 64 + mi * 16 + lr;
            af[mi] = Asb[r * 4 + (lc ^ SW(r))];
        }
        #pragma unroll
        for (int ni = 0; ni < 2; ++ni) {
            int r = wn * 32 + ni * 16 + lr;
            bfr[ni] = Bsb[r * 4 + (lc ^ SW(r))];
        }
        #pragma unroll
        for (int mi = 0; mi < 4; ++mi)
            #pragma unroll
            for (int ni = 0; ni < 2; ++ni)
                acc[mi][ni] = __builtin_amdgcn_mfma_f32_16x16x32_bf16(
                    af[mi], bfr[ni], acc[mi][ni], 0, 0, 0);
    }

    // bf16 epilogue via LDS repack -> coalesced 16B stores
    {
        unsigned short* RP = (unsigned short*)SMEM;  // [64][136] shorts
        float bval[2];
        #pragma unroll
        for (int ni = 0; ni < 2; ++ni) {
            int col = col0 + wn * 32 + ni * 16 + lr;
            bval[ni] = (col < N) ? bias[col] : 0.f;
        }
        #pragma unroll
        for (int h2 = 0; h2 < 2; ++h2) {
            __syncthreads();
            if (wm == h2) {
                #pragma unroll
                for (int ni = 0; ni < 2; ++ni) {
                    int colL = wn * 32 + ni * 16 + lr;
                    #pragma unroll
                    for (int mi = 0; mi < 4; ++mi) {
                        #pragma unroll
                        for (int rg = 0; rg < 4; ++rg) {
                            int rowL = mi * 16 + lc * 4 + rg;
                            RP[rowL * 136 + colL] = f2bf(acc[mi][ni][rg] + bval[ni]);
                        }
                    }
                }
            }
            __syncthreads();
            {
                int r = tid >> 3;          // 0..63
                int c = tid & 7;           // 0..7
                int grow = row0 + h2 * 64 + r;
                if (grow < M) {
                    #pragma unroll
                    for (int j = 0; j < 2; ++j) {
                        int cc = c * 2 + j;            // 0..15
                        int gcol = col0 + cc * 8;
                        uint4 vq = *(const uint4*)&RP[r * 136 + cc * 8];
                        *(uint4*)(C + (size_t)grow * N + gcol) = vq;
                    }
                }
            }
        }
    }
}

// ===========================================================================
// SMALL GEMM: BM=64, BN=64, BK=32; 4 waves (2x2), wave 32x32 (2x2 frags).
// ===========================================================================
#define SLOADA(B, k0) do {                                                    \
    if constexpr (ABF) {                                                      \
        const unsigned short* ap_ = Abf + (size_t)agr * K + (k0) + ah;        \
        qa##B = aok ? *(const uint4*)ap_ : z4;                                \
    } else {                                                                  \
        if (aok) {                                                            \
            const float* ap_ = Afp + (size_t)agr * K + (k0) + ah;             \
            pa##B##0 = *(const f32x4*)(ap_);                                  \
            pa##B##1 = *(const f32x4*)(ap_ + 4);                              \
            if (A2) {                                                         \
                const float* a2_ = A2 + (size_t)agr * K + (k0) + ah;          \
                pa##B##0 += *(const f32x4*)(a2_);                             \
                pa##B##1 += *(const f32x4*)(a2_ + 4);                         \
            }                                                                 \
        } else { pa##B##0 = zf4; pa##B##1 = zf4; }                            \
    }                                                                         \
    { const unsigned short* bp_ = BT + (size_t)bgr * K + (k0) + ah;           \
      pb##B = *(const uint4*)bp_; }                                           \
} while (0)

#define SSTAGE(B) do {                                                        \
    if constexpr (ABF) {                                                      \
        As4[ar * 4 + (ac ^ SW(ar))] = qa##B;                                  \
    } else {                                                                  \
        union { unsigned short us_[8]; uint4 q_; } u_;                        \
        u_.us_[0] = f2bf(pa##B##0[0]); u_.us_[1] = f2bf(pa##B##0[1]);         \
        u_.us_[2] = f2bf(pa##B##0[2]); u_.us_[3] = f2bf(pa##B##0[3]);         \
        u_.us_[4] = f2bf(pa##B##1[0]); u_.us_[5] = f2bf(pa##B##1[1]);         \
        u_.us_[6] = f2bf(pa##B##1[2]); u_.us_[7] = f2bf(pa##B##1[3]);         \
        As4[ar * 4 + (ac ^ SW(ar))] = u_.q_;                                  \
    }                                                                         \
    Bs4[ar * 4 + (ac ^ SW(ar))] = pb##B;                                      \
} while (0)

#define SMFMA() do {                                                          \
    bf16x8 af[2], bfr[2];                                                     \
    _Pragma("unroll")                                                         \
    for (int mi = 0; mi < 2; ++mi) {                                          \
        int r = wm * 32 + mi * 16 + lr;                                       \
        af[mi] = Asb[r * 4 + (lc ^ SW(r))];                                   \
    }                                                                         \
    _Pragma("unroll")                                                         \
    for (int ni = 0; ni < 2; ++ni) {                                          \
        int r = wn * 32 + ni * 16 + lr;                                       \
        bfr[ni] = Bsb[r * 4 + (lc ^ SW(r))];                                  \
    }                                                                         \
    _Pragma("unroll")                                                         \
    for (int mi = 0; mi < 2; ++mi)                                            \
        _Pragma("unroll")                                                     \
        for (int ni = 0; ni < 2; ++ni)                                        \
            acc[mi][ni] = __builtin_amdgcn_mfma_f32_16x16x32_bf16(            \
                af[mi], bfr[ni], acc[mi][ni], 0, 0, 0);                       \
} while (0)

template<int ABF>
__global__ __launch_bounds__(256) void gemm_small(
    const void* __restrict__ Ain, const float* __restrict__ A2,
    const unsigned short* __restrict__ BT, const float* __restrict__ bias,
    void* __restrict__ Cout, int M, int N, int K, int flags)
{
    __shared__ uint4 SMEM[512];
    uint4* As4 = SMEM;
    uint4* Bs4 = SMEM + 256;

    const int tid = threadIdx.x;
    const int lane = tid & 63;
    const int wave = tid >> 6;
    const int wm = wave >> 1;
    const int wn = wave & 1;
    const int row0 = (flags & FLAG_SWAP ? blockIdx.y : blockIdx.x) * 64;
    const int col0 = (flags & FLAG_SWAP ? blockIdx.x : blockIdx.y) * 64;
    if ((flags & FLAG_QKV) && col0 >= 512) A2 = nullptr;

    const float* Afp = (const float*)Ain;
    const unsigned short* Abf = (const unsigned short*)Ain;

    f32x4 acc[2][2];
    #pragma unroll
    for (int i = 0; i < 2; ++i)
        #pragma unroll
        for (int j = 0; j < 2; ++j)
            acc[i][j] = {0.f, 0.f, 0.f, 0.f};

    const int ar = tid >> 2;
    const int ac = tid & 3;
    const int ah = ac * 8;
    const int agr = row0 + ar;
    const bool aok = agr < M;
    const int bgr = col0 + ar;
    const int lr = lane & 15;
    const int lc = lane >> 4;

    const bf16x8* Asb = (const bf16x8*)As4;
    const bf16x8* Bsb = (const bf16x8*)Bs4;
    const uint4 z4 = {0u, 0u, 0u, 0u};
    const f32x4 zf4 = {0.f, 0.f, 0.f, 0.f};

    f32x4 pa00, pa01, pa10, pa11;
    uint4 qa0, qa1;
    uint4 pb0, pb1;

    const int nsteps = K >> 5;
    SLOADA(0, 0);
    for (int s = 0; s < nsteps; s += 2) {
        __syncthreads();
        SSTAGE(0);
        SLOADA(1, (s + 1 < nsteps ? (s + 1) * 32 : 0));
        __syncthreads();
        SMFMA();
        __syncthreads();
        SSTAGE(1);
        SLOADA(0, (s + 2 < nsteps ? (s + 2) * 32 : 0));
        __syncthreads();
        SMFMA();
    }

    const int relu = flags & FLAG_RELU;
    if (!(flags & FLAG_OBF)) {
        float* C = (float*)Cout;
        #pragma unroll
        for (int ni = 0; ni < 2; ++ni) {
            int col = col0 + wn * 32 + ni * 16 + lr;
            if (col >= N) continue;
            float bval = bias[col];
            #pragma unroll
            for (int mi = 0; mi < 2; ++mi) {
                #pragma unroll
                for (int rg = 0; rg < 4; ++rg) {
                    int row = row0 + wm * 32 + mi * 16 + lc * 4 + rg;
                    if (row < M) {
                        float o = acc[mi][ni][rg] + bval;
                        if (relu) o = fmaxf(o, 0.f);
                        C[(size_t)row * N + col] = o;
                    }
                }
            }
        }
    } else {
        unsigned short* RP = (unsigned short*)SMEM;
        unsigned short* C = (unsigned short*)Cout;
        float bval[2];
        #pragma unroll
        for (int ni = 0; ni < 2; ++ni) {
            int col = col0 + wn * 32 + ni * 16 + lr;
            bval[ni] = (col < N) ? bias[col] : 0.f;
        }
        #pragma unroll
        for (int h2 = 0; h2 < 2; ++h2) {
            __syncthreads();
            if (wm == h2) {
                #pragma unroll
                for (int ni = 0; ni < 2; ++ni) {
                    int colL = wn * 32 + ni * 16 + lr;
                    #pragma unroll
                    for (int mi = 0; mi < 2; ++mi) {
                        #pragma unroll
                        for (int rg = 0; rg < 4; ++rg) {
                            int rowL = mi * 16 + lc * 4 + rg;
                            float o = acc[mi][ni][rg] + bval[ni];
                            if (relu) o = fmaxf(o, 0.f);
                            RP[rowL * 72 + colL] = f2bf(o);
                        }
                    }
                }
            }
            __syncthreads();
            {
                int r = tid >> 3;
                int c = tid & 7;
                int grow = row0 + h2 * 32 + r;
                int gcol = col0 + c * 8;
                if (grow < M && gcol < N) {
                    uint4 vq = *(const uint4*)&RP[r * 72 + c * 8];
                    *(uint4*)(C + (size_t)grow * N + gcol) = vq;
                }
            }
        }
    }
}

// ---------------------------------------------------------------------------
// MFMA flash self-attention over fused bf16 QKV [M][768]
// ---------------------------------------------------------------------------
#define QKVS 768
__global__ __launch_bounds__(256) void attn_mfma_kernel(
    const unsigned short* __restrict__ qkv, float* __restrict__ out)
{
    __shared__ uint4 Kls[64 * 4];
    __shared__ uint4 Vtls[32 * 8];

    const int tid = threadIdx.x;
    const int lane = tid & 63;
    const int wave = tid >> 6;
    const int qcol = lane & 15;
    const int g = lane >> 4;
    const int bh = blockIdx.x;
    const int h = bh & 7, b = bh >> 3;
    const int qg = blockIdx.y * 64 + wave * 16 + qcol;
    const int qc = qg < NQ ? qg : NQ - 1;

    bf16x8 qf = *(const bf16x8*)(qkv + ((size_t)(b * NQ + qc)) * QKVS + h * 32 + g * 8);

    float mrun = -3.0e38f, lrun = 0.f;
    f32x4 oacc[2];
    oacc[0] = {0.f, 0.f, 0.f, 0.f};
    oacc[1] = {0.f, 0.f, 0.f, 0.f};
    const f32x4 zacc = {0.f, 0.f, 0.f, 0.f};

    const int kidx = tid >> 2, kdc = tid & 3;
    const int vkp = tid >> 3, vdc = tid & 7;
    const bf16x8* Kb = (const bf16x8*)Kls;
    const bf16x8* Vb = (const bf16x8*)Vtls;
    unsigned int* V32 = (unsigned int*)Vtls;

    for (int jb = 0; jb < NQ; jb += 64) {
        __syncthreads();
        {
            int gk = jb + kidx;
            const uint4 z = {0u, 0u, 0u, 0u};
            uint4 kv = (gk < NQ)
                ? *(const uint4*)(qkv + ((size_t)(b * NQ + gk)) * QKVS + 256 + h * 32 + kdc * 8)
                : z;
            Kls[kidx * 4 + (kdc ^ ((kidx >> 1) & 3))] = kv;
        }
        {
            int k0g = jb + 2 * vkp;
            ushort4 a = {0, 0, 0, 0}, c = {0, 0, 0, 0};
            if (k0g < NQ)
                a = *(const ushort4*)(qkv + ((size_t)(b * NQ + k0g)) * QKVS + 512 + h * 32 + vdc * 4);
            if (k0g + 1 < NQ)
                c = *(const ushort4*)(qkv + ((size_t)(b * NQ + k0g + 1)) * QKVS + 512 + h * 32 + vdc * 4);
            unsigned int p0 = (unsigned int)a.x | ((unsigned int)c.x << 16);
            unsigned int p1 = (unsigned int)a.y | ((unsigned int)c.y << 16);
            unsigned int p2 = (unsigned int)a.z | ((unsigned int)c.z << 16);
            unsigned int p3 = (unsigned int)a.w | ((unsigned int)c.w << 16);
            int d0 = vdc * 4;
            V32[(d0+0) * 32 + ((vkp >> 2) ^ ((d0+0) & 7)) * 4 + (vkp & 3)] = p0;
            V32[(d0+1) * 32 + ((vkp >> 2) ^ ((d0+1) & 7)) * 4 + (vkp & 3)] = p1;
            V32[(d0+2) * 32 + ((vkp >> 2) ^ ((d0+2) & 7)) * 4 + (vkp & 3)] = p2;
            V32[(d0+3) * 32 + ((vkp >> 2) ^ ((d0+3) & 7)) * 4 + (vkp & 3)] = p3;
        }
        __syncthreads();

        f32x4 sacc[4];
        #pragma unroll
        for (int kt = 0; kt < 4; ++kt) {
            int key = kt * 16 + qcol;
            bf16x8 kf = Kb[key * 4 + (g ^ ((key >> 1) & 3))];
            sacc[kt] = __builtin_amdgcn_mfma_f32_16x16x32_bf16(kf, qf, zacc, 0, 0, 0);
        }
        if (jb + 64 > NQ) {
            #pragma unroll
            for (int kt = 0; kt < 4; ++kt)
                #pragma unroll
                for (int r = 0; r < 4; ++r)
                    if (jb + kt * 16 + 4 * g + r >= NQ) sacc[kt][r] = -3.0e38f;
        }

        float mloc = -3.0e38f;
        #pragma unroll
        for (int kt = 0; kt < 4; ++kt)
            #pragma unroll
            for (int r = 0; r < 4; ++r)
                mloc = fmaxf(mloc, sacc[kt][r]);
        mloc = fmaxf(mloc, __shfl_xor(mloc, 16));
        mloc = fmaxf(mloc, __shfl_xor(mloc, 32));
        float mnew = fmaxf(mrun, mloc);
        float corr = __expf(mrun - mnew);
        mrun = mnew;

        float lloc = 0.f;
        unsigned int pk2[4][2];
        #pragma unroll
        for (int kt = 0; kt < 4; ++kt) {
            float p0 = __expf(sacc[kt][0] - mnew);
            float p1 = __expf(sacc[kt][1] - mnew);
            float p2 = __expf(sacc[kt][2] - mnew);
            float p3 = __expf(sacc[kt][3] - mnew);
            lloc += p0 + p1 + p2 + p3;
            pk2[kt][0] = (unsigned int)f2bf(p0) | ((unsigned int)f2bf(p1) << 16);
            pk2[kt][1] = (unsigned int)f2bf(p2) | ((unsigned int)f2bf(p3) << 16);
        }
        lloc += __shfl_xor(lloc, 16);
        lloc += __shfl_xor(lloc, 32);
        lrun = lrun * corr + lloc;
        #pragma unroll
        for (int ni = 0; ni < 2; ++ni)
            #pragma unroll
            for (int r = 0; r < 4; ++r)
                oacc[ni][r] *= corr;

        const int s0 = qcol + 32 * (g & 1);
        const bool hi = (g >> 1) != 0;
        #pragma unroll
        for (int tp = 0; tp < 2; ++tp) {
            int A0 = (int)pk2[2 * tp][0], A1 = (int)pk2[2 * tp][1];
            int B0 = (int)pk2[2 * tp + 1][0], B1 = (int)pk2[2 * tp + 1][1];
            int a0 = __shfl(A0, s0),      a1 = __shfl(A1, s0);
            int b0 = __shfl(B0, s0),      b1 = __shfl(B1, s0);
            int a2 = __shfl(A0, s0 + 16), a3 = __shfl(A1, s0 + 16);
            int b2 = __shfl(B0, s0 + 16), b3 = __shfl(B1, s0 + 16);
            union { unsigned int u[4]; bf16x8 v8; } pf;
            pf.u[0] = hi ? (unsigned int)b0 : (unsigned int)a0;
            pf.u[1] = hi ? (unsigned int)b1 : (unsigned int)a1;
            pf.u[2] = hi ? (unsigned int)b2 : (unsigned int)a2;
            pf.u[3] = hi ? (unsigned int)b3 : (unsigned int)a3;
            #pragma unroll
            for (int ni = 0; ni < 2; ++ni) {
                int d = ni * 16 + qcol;
                bf16x8 vf = Vb[d * 8 + ((4 * tp + g) ^ (d & 7))];
                oacc[ni] = __builtin_amdgcn_mfma_f32_16x16x32_bf16(vf, pf.v8, oacc[ni], 0, 0, 0);
            }
        }
    }

    if (qg < NQ) {
        float inv = 1.f / lrun;
        float* op = out + ((size_t)(b * NQ + qg)) * DM + h * 32;
        float4 o0, o1;
        o0.x = oacc[0][0] * inv; o0.y = oacc[0][1] * inv;
        o0.z = oacc[0][2] * inv; o0.w = oacc[0][3] * inv;
        o1.x = oacc[1][0] * inv; o1.y = oacc[1][1] * inv;
        o1.z = oacc[1][2] * inv; o1.w = oacc[1][3] * inv;
        *(float4*)(op + 4 * g) = o0;
        *(float4*)(op + 16 + 4 * g) = o1;
    }
}

// ---------------------------------------------------------------------------
// Deformable sampling over bf16 value table; offaw [M][384] holds RAW aw
// logits at +256 — softmax over 16 computed inline.
// ---------------------------------------------------------------------------
__global__ __launch_bounds__(256) void deform_kernel(
    const unsigned short* __restrict__ value, const float* __restrict__ offaw,
    const float* __restrict__ rbbox, float* __restrict__ dout)
{
    int t = blockIdx.x * 256 + threadIdx.x;
    if (t >= BS * NQ * 64) return;
    int c = t & 7;
    int h = (t >> 3) & 7;
    int bq = t >> 6;
    int b = bq / NQ;

    const int Hs[4]     = {100, 50, 25, 13};
    const int Wsz[4]    = {100, 50, 25, 13};
    const int Starts[4] = {0, 10000, 12500, 13125};

    float4 rb = *(const float4*)(rbbox + (size_t)bq * 4);
    const float* offp = offaw + (size_t)bq * 384 + h * 32;
    const float* awp  = offaw + (size_t)bq * 384 + 256 + h * 16;
    const unsigned short* vb = value + ((size_t)b * LEN_V) * 256 + h * 32 + c * 4;

    float awv[16];
    #pragma unroll
    for (int i = 0; i < 4; ++i) {
        float4 f = *(const float4*)(awp + i * 4);
        awv[4*i+0] = f.x; awv[4*i+1] = f.y; awv[4*i+2] = f.z; awv[4*i+3] = f.w;
    }
    float mx = awv[0];
    #pragma unroll
    for (int i = 1; i < 16; ++i) mx = fmaxf(mx, awv[i]);
    float ssum = 0.f;
    #pragma unroll
    for (int i = 0; i < 16; ++i) { awv[i] = __expf(awv[i] - mx); ssum += awv[i]; }
    float sinv = 1.f / ssum;

    float4 acc = make_float4(0.f, 0.f, 0.f, 0.f);
    #pragma unroll
    for (int l = 0; l < 4; ++l) {
        const int H = Hs[l], W = Wsz[l], st = Starts[l];
        #pragma unroll
        for (int p = 0; p < 4; ++p) {
            float ox = offp[l * 8 + p * 2 + 0];
            float oy = offp[l * 8 + p * 2 + 1];
            float a_w = awv[l * 4 + p] * sinv;
            float xx = (rb.x + ox * 0.125f * rb.z) * W - 0.5f;
            float yy = (rb.y + oy * 0.125f * rb.w) * H - 0.5f;
            float x0f = floorf(xx), y0f = floorf(yy);
            float fx = xx - x0f, fy = yy - y0f;
            int x0 = (int)x0f, y0 = (int)y0f;
            #pragma unroll
            for (int dy = 0; dy < 2; ++dy) {
                int yi = y0 + dy;
                float wy = dy ? fy : (1.f - fy);
                bool vy = (yi >= 0) && (yi < H);
                int yc = min(max(yi, 0), H - 1);
                #pragma unroll
                for (int dx = 0; dx < 2; ++dx) {
                    int xi = x0 + dx;
                    float wx = dx ? fx : (1.f - fx);
                    bool vx = (xi >= 0) && (xi < W);
                    int xc = min(max(xi, 0), W - 1);
                    float wgt = a_w * wy * wx * ((vx && vy) ? 1.f : 0.f);
                    ushort4 gv = *(const ushort4*)(vb + (size_t)(st + yc * W + xc) * 256);
                    acc.x += wgt * bf2f(gv.x); acc.y += wgt * bf2f(gv.y);
                    acc.z += wgt * bf2f(gv.z); acc.w += wgt * bf2f(gv.w);
                }
            }
        }
    }
    *(float4*)(dout + (size_t)bq * 256 + h * 32 + c * 4) = acc;
}

// ---------------------------------------------------------------------------
__global__ __launch_bounds__(256) void ln_kernel(
    const float* __restrict__ x, const float* __restrict__ dx,
    const float* __restrict__ g, const float* __restrict__ bt,
    float* __restrict__ out, int rows)
{
    int row = blockIdx.x * 4 + (threadIdx.x >> 6);
    if (row >= rows) return;
    int lane = threadIdx.x & 63;
    size_t base = (size_t)row * 256 + lane * 4;
    float4 xv = *(const float4*)(x + base);
    float4 dv = *(const float4*)(dx + base);
    float a0 = xv.x + dv.x, a1 = xv.y + dv.y, a2 = xv.z + dv.z, a3 = xv.w + dv.w;
    float s = a0 + a1 + a2 + a3;
    float s2 = a0 * a0 + a1 * a1 + a2 * a2 + a3 * a3;
    #pragma unroll
    for (int o = 32; o; o >>= 1) {
        s += __shfl_xor(s, o);
        s2 += __shfl_xor(s2, o);
    }
    float mean = s * (1.f / 256.f);
    float var = s2 * (1.f / 256.f) - mean * mean;
    float inv = rsqrtf(var + 1e-5f);
    float4 gv = *(const float4*)(g + lane * 4);
    float4 bv = *(const float4*)(bt + lane * 4);
    float4 r;
    r.x = (a0 - mean) * inv * gv.x + bv.x;
    r.y = (a1 - mean) * inv * gv.y + bv.y;
    r.z = (a2 - mean) * inv * gv.z + bv.z;
    r.w = (a3 - mean) * inv * gv.w + bv.w;
    *(float4*)(out + base) = r;
}

// ---------------------------------------------------------------------------
extern "C" void kernel_launch(void* const* d_in, const int* in_sizes, int n_in,
                              void* d_out, int out_size, void* d_ws, size_t ws_size,
                              hipStream_t stream)
{
    const float* embed = (const float*)d_in[0];
    const float* rbbox = (const float*)d_in[1];
    const float* feats = (const float*)d_in[2];
    const float* qpos  = (const float*)d_in[3];
    const float* Wq = (const float*)d_in[4];  const float* bq = (const float*)d_in[5];
    const float* Wk = (const float*)d_in[6];  const float* bk = (const float*)d_in[7];
    const float* Wv = (const float*)d_in[8];  const float* bv = (const float*)d_in[9];
    const float* Wo = (const float*)d_in[10]; const float* bo = (const float*)d_in[11];
    const float* g1 = (const float*)d_in[12]; const float* b1 = (const float*)d_in[13];
    const float* Wval = (const float*)d_in[14]; const float* bval = (const float*)d_in[15];
    const float* Woff = (const float*)d_in[16]; const float* boff = (const float*)d_in[17];
    const float* Waw  = (const float*)d_in[18]; const float* baw  = (const float*)d_in[19];
    const float* Wop  = (const float*)d_in[20]; const float* bop  = (const float*)d_in[21];
    const float* g2 = (const float*)d_in[22]; const float* b2 = (const float*)d_in[23];
    const float* W1 = (const float*)d_in[24]; const float* bf1 = (const float*)d_in[25];
    const float* W2 = (const float*)d_in[26]; const float* bf2 = (const float*)d_in[27];
    const float* g3 = (const float*)d_in[28]; const float* b3 = (const float*)d_in[29];

    const int M = BS * NQ;                 // 7200
    const int MV = BS * LEN_V;             // 106352
    const size_t E = (size_t)M * DM;       // 1,843,200 floats
    const size_t VAL = (size_t)MV * DM;    // value region (floats)

    float* ws = (float*)d_ws;
    float* valueb = ws;
    float* qkvreg = ws + VAL;
    float* attb   = qkvreg + 3 * E;
    float* e1b    = attb + E;
    unsigned short* wbase = (unsigned short*)(e1b + E);
    unsigned short* wqkv_t   = wbase;                     // 768*256
    unsigned short* wo_t     = wbase + 196608;
    unsigned short* wval_t   = wbase + 262144;
    unsigned short* woffaw_t = wbase + 327680;
    unsigned short* wop_t    = wbase + 425984;
    unsigned short* w1_t     = wbase + 491520;
    unsigned short* w2_t     = wbase + 753664;
    float* bqkv   = (float*)(wbase + 1015808);
    float* boffaw = bqkv + 768;

    unsigned short* valuebf = (unsigned short*)valueb;
    unsigned short* qkvbf   = (unsigned short*)qkvreg;
    float* sab    = qkvreg;
    float* offawb = qkvreg + E;
    float* doutb  = attb;
    float* cab    = qkvreg;
    float* e2b    = qkvreg + 2 * E;
    unsigned short* ffhb = (unsigned short*)valueb;
    float* ffb    = attb;

    dim3 blk(256);
    auto gsS = [](int m, int n) { return dim3((n + 63) / 64, (m + 63) / 64); };

    // 0: weight + bias prep (Wq pre-scaled by 1/sqrt(HEAD_DIM))
    {
        const float sc = 0.17677669529663687f;
        WPrepArgs a;
        a.w[0] = {Wq,   wqkv_t,                 256, 256,  sc};
        a.w[1] = {Wk,   wqkv_t + 256 * 256,     256, 256,  1.f};
        a.w[2] = {Wv,   wqkv_t + 512 * 256,     256, 256,  1.f};
        a.w[3] = {Wo,   wo_t,                   256, 256,  1.f};
        a.w[4] = {Wval, wval_t,                 256, 256,  1.f};
        a.w[5] = {Woff, woffaw_t,               256, 256,  1.f};
        a.w[6] = {Waw,  woffaw_t + 256 * 256,   256, 128,  1.f};
        a.w[7] = {Wop,  wop_t,                  256, 256,  1.f};
        a.w[8] = {W1,   w1_t,                   256, 1024, 1.f};
        a.w[9] = {W2,   w2_t,                   1024, 256, 1.f};
        wprep_kernel<<<dim3(32, 32, 10), blk, 0, stream>>>(a);
        bias_concat_kernel<<<dim3(3), blk, 0, stream>>>(bq, bk, bv, boff, baw, bqkv, boffaw);
    }

    // 1: fused QKV projection -> bf16 [M][768]
    gemm_small<0><<<gsS(M, 768), blk, 0, stream>>>(embed, qpos, wqkv_t, bqkv, qkvbf, M, 768, 256, FLAG_SWAP | FLAG_QKV | FLAG_OBF);
    // 2: self-attention (MFMA flash, bf16 inputs)
    attn_mfma_kernel<<<dim3(BS * 8, (NQ + 63) / 64), blk, 0, stream>>>(qkvbf, attb);
    // 3: output projection
    gemm_small<0><<<gsS(M, 256), blk, 0, stream>>>(attb, nullptr, wo_t, bo, sab, M, 256, 256, FLAG_SWAP);
    // 4: LN1
    ln_kernel<<<dim3((M + 3) / 4), blk, 0, stream>>>(embed, sab, g1, b1, e1b, M);
    // 5: value projection (round-14 proven occupancy-first GEMM) -> bf16
    gemm_val2<<<dim3(2, (MV + 127) / 128), dim3(512), 0, stream>>>(feats, wval_t, bval, valuebf, MV, 256, 256);
    // 6: fused offsets + aw logits (query = e1 + qpos); softmax fused into deform
    gemm_small<0><<<gsS(M, 384), blk, 0, stream>>>(e1b, qpos, woffaw_t, boffaw, offawb, M, 384, 256, FLAG_SWAP);
    // 7: deformable sampling (bf16 gathers, inline aw softmax)
    deform_kernel<<<dim3((BS * NQ * 64 + 255) / 256), blk, 0, stream>>>(valuebf, offawb, rbbox, doutb);
    // 8: output projection of deformable attention
    gemm_small<0><<<gsS(M, 256), blk, 0, stream>>>(doutb, nullptr, wop_t, bop, cab, M, 256, 256, FLAG_SWAP);
    // 9: LN2
    ln_kernel<<<dim3((M + 3) / 4), blk, 0, stream>>>(e1b, cab, g2, b2, e2b, M);
    // 10: FFN1 (relu) -> bf16 hidden
    gemm_small<0><<<gsS(M, 1024), blk, 0, stream>>>(e2b, nullptr, w1_t, bf1, ffhb, M, 1024, 256, FLAG_SWAP | FLAG_RELU | FLAG_OBF);
    // 11: FFN2 (bf16 A, K=1024)
    gemm_small<1><<<gsS(M, 256), blk, 0, stream>>>(ffhb, nullptr, w2_t, bf2, ffb, M, 256, 1024, FLAG_SWAP);
    // 12: LN3 -> out
    ln_kernel<<<dim3((M + 3) / 4), blk, 0, stream>>>(e2b, ffb, g3, b3, (float*)d_out, M);
}